// Round 37
// baseline (4337.106 us; speedup 1.0000x reference)
//
#include <hip/hip_runtime.h>
#include <math.h>

#define TT 16384      // B*S tokens
#define DD 2048       // hidden dim
#define EE 64         // experts
#define KTOP 8
#define BM 64         // rows per block (grid 256 = 1 block/CU)
#define BK 64         // k-chunk (32 tiles; mid-tile fold at kt=28)
#define NT (DD / BK)  // 32 k-tiles
#define SL 4096       // seq len
#define BB 4          // batch
#define NTHR 1024     // 16 waves/block = 4 waves/SIMD
#define TSTR 68       // LDS tile stride (64 + 4 pad)

// numpy SIMD float32 exp (P/Q rational — locked)
__device__ __forceinline__ float np_expf(float x) {
    const float LOG2E = 1.442695040888963407359924681001892137f;
    const float MAGIC = 0x1.800000p+23f;
    const float C1 = -6.93145752e-1f;
    const float C2 = -1.42860677e-6f;
    float q = __fmul_rn(x, LOG2E);
    q = __fadd_rn(q, MAGIC);
    q = __fsub_rn(q, MAGIC);
    x = __fmaf_rn(q, C1, x);
    x = __fmaf_rn(q, C2, x);
    float num = __fmaf_rn(5.082762527590693718096e-04f, x, 6.757896990527504603057e-03f);
    num = __fmaf_rn(num, x, 5.114512081637298353406e-02f);
    num = __fmaf_rn(num, x, 2.473615434895520810817e-01f);
    num = __fmaf_rn(num, x, 7.257664613233124478488e-01f);
    num = __fmaf_rn(num, x, 9.999999999980870924916e-01f);
    float den = __fmaf_rn(2.159509375685829852307e-02f, x, -2.742335390411667452936e-01f);
    den = __fmaf_rn(den, x, 1.0f);
    const float quot = __fdiv_rn(num, den);
    const int qi = (int)q;
    const float sc = __uint_as_float((unsigned int)(127 + qi) << 23);
    return __fmul_rn(quot, sc);
}

// GEMM arithmetic (LOCKED): OpenBLAS skylakex — K chunks [320 x5, 224, 224];
// folds at global k in {320,640,960,1280,1600,1824,2048}; 2 banks,
// bank=(k>>2)&1, TREE combine (c0+c1), one f32 add into C per chunk.
// BK=64: tile-end folds at kt+1 in {5,10,15,20,25,32}; mid-tile fold in
// kt==28 after kk==31 (k=1824).
__device__ __forceinline__ bool is_fold_end(int kt1) {
    return kt1 == 5 || kt1 == 10 || kt1 == 15 || kt1 == 20 ||
           kt1 == 25 || kt1 == 32;
}

__global__ __launch_bounds__(NTHR) void moe_gate_main(
    const float* __restrict__ X, const float* __restrict__ W,
    float* __restrict__ out, float* __restrict__ ws_cnt, float* __restrict__ ws_ssum)
{
    __shared__ float Xs[2][BK * TSTR];     // [kk][r]  34.8 KB
    __shared__ float Wsh[2][BK * TSTR];    // [kk][e]  34.8 KB
    __shared__ float Ls[BM * TSTR];        // 17.4 KB
    __shared__ float mrow[BM], zrow[BM];
    __shared__ float cnt[EE];

    const int tid  = threadIdx.x;
    const int row0 = blockIdx.x * BM;
    const int tr   = tid >> 4;    // 0..63 -> row
    const int tc   = tid & 15;    // 0..15 -> cols 4tc..4tc+3

    float tot[4], acc[2][4];
#pragma unroll
    for (int j = 0; j < 4; ++j) { tot[j] = 0.f; acc[0][j] = 0.f; acc[1][j] = 0.f; }

    if (tid < EE) cnt[tid] = 0.f;

    // staging: X 64x64=4096 el (4/thread), W 4096 el (4/thread); coalesced
    const float* xptr[4]; int xdst[4];
    const float* wptr[4]; int wdst[4];
#pragma unroll
    for (int j = 0; j < 4; ++j) {
        const int el = j * NTHR + tid;
        const int r = el >> 6, kk = el & 63;
        xptr[j] = X + (size_t)(row0 + r) * DD + kk;
        xdst[j] = kk * TSTR + r;
        wptr[j] = W + (size_t)r * DD + kk;
        wdst[j] = kk * TSTR + r;
    }

    float xr[4], wr[4];
#pragma unroll
    for (int j = 0; j < 4; ++j) { xr[j] = *xptr[j]; xptr[j] += BK; }
#pragma unroll
    for (int j = 0; j < 4; ++j) { wr[j] = *wptr[j]; wptr[j] += BK; }
#pragma unroll
    for (int j = 0; j < 4; ++j) Xs[0][xdst[j]] = xr[j];
#pragma unroll
    for (int j = 0; j < 4; ++j) Wsh[0][wdst[j]] = wr[j];

    for (int kt = 0; kt < NT; ++kt) {
        __syncthreads();
        const int cur = kt & 1;
        if (kt + 1 < NT) {   // issue next-tile global loads early
#pragma unroll
            for (int j = 0; j < 4; ++j) { xr[j] = *xptr[j]; xptr[j] += BK; }
#pragma unroll
            for (int j = 0; j < 4; ++j) { wr[j] = *wptr[j]; wptr[j] += BK; }
        }
        // locked chain: ascending kk, bank=(kk>>2)&1; X scalar broadcast,
        // W b128; mid-tile fold at kt==28 after kk==31 (k=1824)
#pragma unroll
        for (int kk = 0; kk < BK; ++kk) {
            const int p = (kk >> 2) & 1;
            const float xv = Xs[cur][kk * TSTR + tr];
            const float4 b = *(const float4*)&Wsh[cur][kk * TSTR + 4 * tc];
            acc[p][0] = __fmaf_rn(xv, b.x, acc[p][0]);
            acc[p][1] = __fmaf_rn(xv, b.y, acc[p][1]);
            acc[p][2] = __fmaf_rn(xv, b.z, acc[p][2]);
            acc[p][3] = __fmaf_rn(xv, b.w, acc[p][3]);
            if (kk == 31) {
                if (kt == 28) {   // fold at k=1824
#pragma unroll
                    for (int j = 0; j < 4; ++j) {
                        tot[j] = __fadd_rn(tot[j], __fadd_rn(acc[0][j], acc[1][j]));
                        acc[0][j] = 0.f; acc[1][j] = 0.f;
                    }
                }
            }
        }
        if (is_fold_end(kt + 1)) {
#pragma unroll
            for (int j = 0; j < 4; ++j) {
                tot[j] = __fadd_rn(tot[j], __fadd_rn(acc[0][j], acc[1][j]));
                acc[0][j] = 0.f; acc[1][j] = 0.f;
            }
        }
        if (kt + 1 < NT) {
#pragma unroll
            for (int j = 0; j < 4; ++j) Xs[cur ^ 1][xdst[j]] = xr[j];
#pragma unroll
            for (int j = 0; j < 4; ++j) Wsh[cur ^ 1][wdst[j]] = wr[j];
        }
    }

    // logits -> LDS
    {
        float4 v; v.x = tot[0]; v.y = tot[1]; v.z = tot[2]; v.w = tot[3];
        *(float4*)&Ls[tr * TSTR + 4 * tc] = v;
    }
    __syncthreads();

    // P1: row max (64 threads = 1 wave)
    if (tid < BM) {
        const int r = tid;
        float m = Ls[r * TSTR];
#pragma unroll
        for (int e = 1; e < EE; ++e) m = fmaxf(m, Ls[r * TSTR + e]);
        mrow[r] = m;
    }
    __syncthreads();

    // P2: u = np.exp(l - m), in place (1024 thr x 4)
#pragma unroll
    for (int j = 0; j < 4; ++j) {
        const int q2 = j * NTHR + tid;
        const int r = q2 >> 6, e = q2 & 63;
        Ls[r * TSTR + e] = np_expf(__fsub_rn(Ls[r * TSTR + e], mrow[r]));
    }
    __syncthreads();

    // P3: z per row — numpy pairwise (8 accumulators, exact order)
    if (tid < BM) {
        const int r = tid;
        float rr8[8];
#pragma unroll
        for (int j = 0; j < 8; ++j) rr8[j] = Ls[r * TSTR + j];
#pragma unroll
        for (int c = 1; c < 8; ++c)
#pragma unroll
            for (int j = 0; j < 8; ++j)
                rr8[j] = __fadd_rn(rr8[j], Ls[r * TSTR + 8 * c + j]);
        zrow[r] = __fadd_rn(
            __fadd_rn(__fadd_rn(rr8[0], rr8[1]), __fadd_rn(rr8[2], rr8[3])),
            __fadd_rn(__fadd_rn(rr8[4], rr8[5]), __fadd_rn(rr8[6], rr8[7])));
    }
    __syncthreads();

    // P4: s = u / z, in place
#pragma unroll
    for (int j = 0; j < 4; ++j) {
        const int q2 = j * NTHR + tid;
        const int r = q2 >> 6, e = q2 & 63;
        Ls[r * TSTR + e] = __fdiv_rn(Ls[r * TSTR + e], zrow[r]);
    }
    __syncthreads();

    // P5: top-8 per row (64 threads) — value desc, index ASC on exact ties
    if (tid < BM) {
        const int r = tid;
        float s[EE];
#pragma unroll
        for (int q2 = 0; q2 < 16; ++q2) {
            const float4 v = *(const float4*)&Ls[r * TSTR + 4 * q2];
            s[4 * q2] = v.x; s[4 * q2 + 1] = v.y; s[4 * q2 + 2] = v.z; s[4 * q2 + 3] = v.w;
        }
        float pv = 3.4e38f; int pi = -1;
        float wk[KTOP]; int ti[KTOP]; float wsum = 0.f;
#pragma unroll
        for (int k = 0; k < KTOP; ++k) {
            float best = -3.4e38f; int bi = 0;
#pragma unroll
            for (int e = 0; e < EE; ++e) {
                const bool elig   = (s[e] < pv) || ((s[e] == pv) && (e > pi));
                const bool better = elig && (s[e] > best);
                best = better ? s[e] : best;
                bi   = better ? e    : bi;
            }
            wk[k] = best; ti[k] = bi; wsum = __fadd_rn(wsum, best);
            pv = best; pi = bi;
        }
        const float den = __fadd_rn(wsum, 1e-20f);

        const size_t t = (size_t)row0 + r;
        float4 o0, o1;
        o0.x = (float)ti[0]; o0.y = (float)ti[1]; o0.z = (float)ti[2]; o0.w = (float)ti[3];
        o1.x = (float)ti[4]; o1.y = (float)ti[5]; o1.z = (float)ti[6]; o1.w = (float)ti[7];
        *(float4*)&out[t * 8]     = o0;
        *(float4*)&out[t * 8 + 4] = o1;
        float* outw = out + (size_t)TT * KTOP;
        o0.x = __fdiv_rn(wk[0], den); o0.y = __fdiv_rn(wk[1], den);
        o0.z = __fdiv_rn(wk[2], den); o0.w = __fdiv_rn(wk[3], den);
        o1.x = __fdiv_rn(wk[4], den); o1.y = __fdiv_rn(wk[5], den);
        o1.z = __fdiv_rn(wk[6], den); o1.w = __fdiv_rn(wk[7], den);
        *(float4*)&outw[t * 8]     = o0;
        *(float4*)&outw[t * 8 + 4] = o1;

#pragma unroll
        for (int k = 0; k < KTOP; ++k) atomicAdd(&cnt[ti[k]], 1.f);
    }
    __syncthreads();

    // P6: per-expert column sums (scores still in Ls)
    if (tid < EE) {
        const int e = tid;
        float cs = 0.f;
#pragma unroll
        for (int r2 = 0; r2 < BM; ++r2) cs += Ls[r2 * TSTR + e];
        const int b = row0 / SL;
        atomicAdd(&ws_ssum[b * EE + e], cs);
        atomicAdd(&ws_cnt[b * EE + e], cnt[e]);
    }
}

__global__ void moe_gate_aux(const float* __restrict__ ws_cnt,
                             const float* __restrict__ ws_ssum,
                             float* __restrict__ out_aux)
{
    __shared__ float red[4];
    const int tid = threadIdx.x;  // 256 = B*E cells
    float v = ws_cnt[tid] * ws_ssum[tid];
#pragma unroll
    for (int m = 32; m; m >>= 1) v += __shfl_xor(v, m, 64);
    if ((tid & 63) == 0) red[tid >> 6] = v;
    __syncthreads();
    if (tid == 0) {
        const float tot = red[0] + red[1] + red[2] + red[3];
        // aux = ALPHA * (1/B) * sum_{b,e} (cnt/(S*K/E)) * (ssum/S)
        out_aux[0] = tot * (1e-3f / ((float)BB * 512.f * (float)SL));
    }
}

extern "C" void kernel_launch(void* const* d_in, const int* in_sizes, int n_in,
                              void* d_out, int out_size, void* d_ws, size_t ws_size,
                              hipStream_t stream)
{
    const float* X = (const float*)d_in[0];
    const float* W = (const float*)d_in[1];
    float* out  = (float*)d_out;
    float* cnt  = (float*)d_ws;
    float* ssum = cnt + BB * EE;
    hipMemsetAsync(d_ws, 0, 2 * BB * EE * sizeof(float), stream);
    moe_gate_main<<<TT / BM, NTHR, 0, stream>>>(X, W, out, cnt, ssum);
    moe_gate_aux<<<1, 256, 0, stream>>>(cnt, ssum, out + (size_t)2 * TT * KTOP);
}

// Round 38
// 199.165 us; speedup vs baseline: 21.7764x; 21.7764x over previous
//
#include <hip/hip_runtime.h>
#include <math.h>

#define TT 16384      // B*S tokens
#define DD 2048       // hidden dim
#define EE 64         // experts
#define KTOP 8
#define BM 64         // rows per block (grid 256 = 1 block/CU)
#define BK 64         // k-chunk (32 tiles; mid-tile fold at kt=28)
#define NT (DD / BK)  // 32 k-tiles
#define SL 4096       // seq len
#define BB 4          // batch
#define NTHR 512      // 8 waves/block (VGPR cap 128 — no spill)
#define TSTR 68       // LDS tile stride (64 + 4 pad)

// numpy SIMD float32 exp (P/Q rational — locked)
__device__ __forceinline__ float np_expf(float x) {
    const float LOG2E = 1.442695040888963407359924681001892137f;
    const float MAGIC = 0x1.800000p+23f;
    const float C1 = -6.93145752e-1f;
    const float C2 = -1.42860677e-6f;
    float q = __fmul_rn(x, LOG2E);
    q = __fadd_rn(q, MAGIC);
    q = __fsub_rn(q, MAGIC);
    x = __fmaf_rn(q, C1, x);
    x = __fmaf_rn(q, C2, x);
    float num = __fmaf_rn(5.082762527590693718096e-04f, x, 6.757896990527504603057e-03f);
    num = __fmaf_rn(num, x, 5.114512081637298353406e-02f);
    num = __fmaf_rn(num, x, 2.473615434895520810817e-01f);
    num = __fmaf_rn(num, x, 7.257664613233124478488e-01f);
    num = __fmaf_rn(num, x, 9.999999999980870924916e-01f);
    float den = __fmaf_rn(2.159509375685829852307e-02f, x, -2.742335390411667452936e-01f);
    den = __fmaf_rn(den, x, 1.0f);
    const float quot = __fdiv_rn(num, den);
    const int qi = (int)q;
    const float sc = __uint_as_float((unsigned int)(127 + qi) << 23);
    return __fmul_rn(quot, sc);
}

// GEMM arithmetic (LOCKED, verified @R37): OpenBLAS skylakex — K chunks
// [320 x5, 224, 224]; folds at global k in {320,640,960,1280,1600,1824,2048};
// 2 banks, bank=(k>>2)&1, TREE combine (c0+c1), one f32 add into C per chunk.
// BK=64: tile-end folds at kt+1 in {5,10,15,20,25,32}; mid-tile fold at
// kt==28 after kk==31 (k=1824).
__device__ __forceinline__ bool is_fold_end(int kt1) {
    return kt1 == 5 || kt1 == 10 || kt1 == 15 || kt1 == 20 ||
           kt1 == 25 || kt1 == 32;
}

__global__ __launch_bounds__(NTHR) void moe_gate_main(
    const float* __restrict__ X, const float* __restrict__ W,
    float* __restrict__ out, float* __restrict__ ws_cnt, float* __restrict__ ws_ssum)
{
    __shared__ float Xs[2][BK * TSTR];     // [kk][r]  34.8 KB
    __shared__ float Wsh[2][BK * TSTR];    // [kk][e]  34.8 KB
    __shared__ float Ls[BM * TSTR];        // 17.4 KB
    __shared__ float mrow[BM], zrow[BM];
    __shared__ float cnt[EE];

    const int tid  = threadIdx.x;
    const int row0 = blockIdx.x * BM;
    const int tr   = tid >> 4;    // 0..31 -> rows 2tr, 2tr+1
    const int tc   = tid & 15;    // 0..15 -> cols 4tc..4tc+3

    float tot[2][4], acc[2][2][4];
#pragma unroll
    for (int i = 0; i < 2; ++i)
#pragma unroll
        for (int j = 0; j < 4; ++j) {
            tot[i][j] = 0.f; acc[0][i][j] = 0.f; acc[1][i][j] = 0.f;
        }

    if (tid < EE) cnt[tid] = 0.f;

    // staging: X 64x64=4096 el (8/thread), W 4096 el (8/thread); coalesced.
    // Single base + compile-time offsets (j*8*DD global, j*8 LDS) -> few VGPRs.
    const int srow = tid >> 6;       // 0..7
    const int skk  = tid & 63;       // 0..63
    const float* xbase = X + (size_t)(row0 + srow) * DD + skk;
    const float* wbase = W + (size_t)srow * DD + skk;
    const int dst0 = skk * TSTR + srow;

    float xr[8], wr[8];
#pragma unroll
    for (int j = 0; j < 8; ++j) xr[j] = xbase[(size_t)j * 8 * DD];
#pragma unroll
    for (int j = 0; j < 8; ++j) wr[j] = wbase[(size_t)j * 8 * DD];
    xbase += BK; wbase += BK;
#pragma unroll
    for (int j = 0; j < 8; ++j) Xs[0][dst0 + j * 8] = xr[j];
#pragma unroll
    for (int j = 0; j < 8; ++j) Wsh[0][dst0 + j * 8] = wr[j];

    for (int kt = 0; kt < NT; ++kt) {
        __syncthreads();
        const int cur = kt & 1;
        if (kt + 1 < NT) {   // issue next-tile global loads early
#pragma unroll
            for (int j = 0; j < 8; ++j) xr[j] = xbase[(size_t)j * 8 * DD];
#pragma unroll
            for (int j = 0; j < 8; ++j) wr[j] = wbase[(size_t)j * 8 * DD];
            xbase += BK; wbase += BK;
        }
        // locked chain: ascending kk, bank=(kk>>2)&1; X b64 + W b128;
        // mid-tile fold at kt==28 after kk==31 (k=1824)
#pragma unroll
        for (int kk = 0; kk < BK; ++kk) {
            const int p = (kk >> 2) & 1;
            const float2 a = *(const float2*)&Xs[cur][kk * TSTR + 2 * tr];
            const float4 b = *(const float4*)&Wsh[cur][kk * TSTR + 4 * tc];
            acc[p][0][0] = __fmaf_rn(a.x, b.x, acc[p][0][0]);
            acc[p][0][1] = __fmaf_rn(a.x, b.y, acc[p][0][1]);
            acc[p][0][2] = __fmaf_rn(a.x, b.z, acc[p][0][2]);
            acc[p][0][3] = __fmaf_rn(a.x, b.w, acc[p][0][3]);
            acc[p][1][0] = __fmaf_rn(a.y, b.x, acc[p][1][0]);
            acc[p][1][1] = __fmaf_rn(a.y, b.y, acc[p][1][1]);
            acc[p][1][2] = __fmaf_rn(a.y, b.z, acc[p][1][2]);
            acc[p][1][3] = __fmaf_rn(a.y, b.w, acc[p][1][3]);
            if (kk == 31 && kt == 28) {   // fold at k=1824
#pragma unroll
                for (int i = 0; i < 2; ++i)
#pragma unroll
                    for (int j = 0; j < 4; ++j) {
                        tot[i][j] = __fadd_rn(tot[i][j],
                                              __fadd_rn(acc[0][i][j], acc[1][i][j]));
                        acc[0][i][j] = 0.f; acc[1][i][j] = 0.f;
                    }
            }
        }
        if (is_fold_end(kt + 1)) {
#pragma unroll
            for (int i = 0; i < 2; ++i)
#pragma unroll
                for (int j = 0; j < 4; ++j) {
                    tot[i][j] = __fadd_rn(tot[i][j],
                                          __fadd_rn(acc[0][i][j], acc[1][i][j]));
                    acc[0][i][j] = 0.f; acc[1][i][j] = 0.f;
                }
        }
        if (kt + 1 < NT) {
#pragma unroll
            for (int j = 0; j < 8; ++j) Xs[cur ^ 1][dst0 + j * 8] = xr[j];
#pragma unroll
            for (int j = 0; j < 8; ++j) Wsh[cur ^ 1][dst0 + j * 8] = wr[j];
        }
    }

    // logits -> LDS
#pragma unroll
    for (int i = 0; i < 2; ++i) {
        float4 v; v.x = tot[i][0]; v.y = tot[i][1]; v.z = tot[i][2]; v.w = tot[i][3];
        *(float4*)&Ls[(2 * tr + i) * TSTR + 4 * tc] = v;
    }
    __syncthreads();

    // P1: row max (64 threads)
    if (tid < BM) {
        const int r = tid;
        float m = Ls[r * TSTR];
#pragma unroll
        for (int e = 1; e < EE; ++e) m = fmaxf(m, Ls[r * TSTR + e]);
        mrow[r] = m;
    }
    __syncthreads();

    // P2: u = np.exp(l - m), in place (512 thr x 8)
#pragma unroll
    for (int j = 0; j < 8; ++j) {
        const int q2 = j * NTHR + tid;
        const int r = q2 >> 6, e = q2 & 63;
        Ls[r * TSTR + e] = np_expf(__fsub_rn(Ls[r * TSTR + e], mrow[r]));
    }
    __syncthreads();

    // P3: z per row — numpy pairwise (8 accumulators, exact order)
    if (tid < BM) {
        const int r = tid;
        float rr8[8];
#pragma unroll
        for (int j = 0; j < 8; ++j) rr8[j] = Ls[r * TSTR + j];
#pragma unroll
        for (int c = 1; c < 8; ++c)
#pragma unroll
            for (int j = 0; j < 8; ++j)
                rr8[j] = __fadd_rn(rr8[j], Ls[r * TSTR + 8 * c + j]);
        zrow[r] = __fadd_rn(
            __fadd_rn(__fadd_rn(rr8[0], rr8[1]), __fadd_rn(rr8[2], rr8[3])),
            __fadd_rn(__fadd_rn(rr8[4], rr8[5]), __fadd_rn(rr8[6], rr8[7])));
    }
    __syncthreads();

    // P4: s = u / z, in place
#pragma unroll
    for (int j = 0; j < 8; ++j) {
        const int q2 = j * NTHR + tid;
        const int r = q2 >> 6, e = q2 & 63;
        Ls[r * TSTR + e] = __fdiv_rn(Ls[r * TSTR + e], zrow[r]);
    }
    __syncthreads();

    // P5: top-8 per row (64 threads) — value desc, index ASC on exact ties
    if (tid < BM) {
        const int r = tid;
        float s[EE];
#pragma unroll
        for (int q2 = 0; q2 < 16; ++q2) {
            const float4 v = *(const float4*)&Ls[r * TSTR + 4 * q2];
            s[4 * q2] = v.x; s[4 * q2 + 1] = v.y; s[4 * q2 + 2] = v.z; s[4 * q2 + 3] = v.w;
        }
        float pv = 3.4e38f; int pi = -1;
        float wk[KTOP]; int ti[KTOP]; float wsum = 0.f;
#pragma unroll
        for (int k = 0; k < KTOP; ++k) {
            float best = -3.4e38f; int bi = 0;
#pragma unroll
            for (int e = 0; e < EE; ++e) {
                const bool elig   = (s[e] < pv) || ((s[e] == pv) && (e > pi));
                const bool better = elig && (s[e] > best);
                best = better ? s[e] : best;
                bi   = better ? e    : bi;
            }
            wk[k] = best; ti[k] = bi; wsum = __fadd_rn(wsum, best);
            pv = best; pi = bi;
        }
        const float den = __fadd_rn(wsum, 1e-20f);

        const size_t t = (size_t)row0 + r;
        float4 o0, o1;
        o0.x = (float)ti[0]; o0.y = (float)ti[1]; o0.z = (float)ti[2]; o0.w = (float)ti[3];
        o1.x = (float)ti[4]; o1.y = (float)ti[5]; o1.z = (float)ti[6]; o1.w = (float)ti[7];
        *(float4*)&out[t * 8]     = o0;
        *(float4*)&out[t * 8 + 4] = o1;
        float* outw = out + (size_t)TT * KTOP;
        o0.x = __fdiv_rn(wk[0], den); o0.y = __fdiv_rn(wk[1], den);
        o0.z = __fdiv_rn(wk[2], den); o0.w = __fdiv_rn(wk[3], den);
        o1.x = __fdiv_rn(wk[4], den); o1.y = __fdiv_rn(wk[5], den);
        o1.z = __fdiv_rn(wk[6], den); o1.w = __fdiv_rn(wk[7], den);
        *(float4*)&outw[t * 8]     = o0;
        *(float4*)&outw[t * 8 + 4] = o1;

#pragma unroll
        for (int k = 0; k < KTOP; ++k) atomicAdd(&cnt[ti[k]], 1.f);
    }
    __syncthreads();

    // P6: per-expert column sums (scores still in Ls)
    if (tid < EE) {
        const int e = tid;
        float cs = 0.f;
#pragma unroll
        for (int r2 = 0; r2 < BM; ++r2) cs += Ls[r2 * TSTR + e];
        const int b = row0 / SL;
        atomicAdd(&ws_ssum[b * EE + e], cs);
        atomicAdd(&ws_cnt[b * EE + e], cnt[e]);
    }
}

__global__ void moe_gate_aux(const float* __restrict__ ws_cnt,
                             const float* __restrict__ ws_ssum,
                             float* __restrict__ out_aux)
{
    __shared__ float red[4];
    const int tid = threadIdx.x;  // 256 = B*E cells
    float v = ws_cnt[tid] * ws_ssum[tid];
#pragma unroll
    for (int m = 32; m; m >>= 1) v += __shfl_xor(v, m, 64);
    if ((tid & 63) == 0) red[tid >> 6] = v;
    __syncthreads();
    if (tid == 0) {
        const float tot = red[0] + red[1] + red[2] + red[3];
        // aux = ALPHA * (1/B) * sum_{b,e} (cnt/(S*K/E)) * (ssum/S)
        out_aux[0] = tot * (1e-3f / ((float)BB * 512.f * (float)SL));
    }
}

extern "C" void kernel_launch(void* const* d_in, const int* in_sizes, int n_in,
                              void* d_out, int out_size, void* d_ws, size_t ws_size,
                              hipStream_t stream)
{
    const float* X = (const float*)d_in[0];
    const float* W = (const float*)d_in[1];
    float* out  = (float*)d_out;
    float* cnt  = (float*)d_ws;
    float* ssum = cnt + BB * EE;
    hipMemsetAsync(d_ws, 0, 2 * BB * EE * sizeof(float), stream);
    moe_gate_main<<<TT / BM, NTHR, 0, stream>>>(X, W, out, cnt, ssum);
    moe_gate_aux<<<1, 256, 0, stream>>>(cnt, ssum, out + (size_t)2 * TT * KTOP);
}